// Round 10
// baseline (410.296 us; speedup 1.0000x reference)
//
#include <hip/hip_runtime.h>
#include <cstdint>

// Problem constants (from reference)
#define TSEQ 224
#define HID 128
#define NSEQ 1280           // BATCHES*SUB = 64*20
#define KTOT (TSEQ*HID)     // 28672
#define NB 16               // sequences per LSTM block
#define INTER 64
#define SUB 20

typedef short bf16x8 __attribute__((ext_vector_type(8)));
typedef float f32x4  __attribute__((ext_vector_type(4)));

__device__ __forceinline__ float fast_sigmoid(float a) {
  float e = __expf(-a);
  return __builtin_amdgcn_rcpf(1.0f + e);
}
__device__ __forceinline__ float fast_tanh(float a) {
  float e = __expf(-2.0f * a);
  return fmaf(2.0f, __builtin_amdgcn_rcpf(1.0f + e), -1.0f);
}

// Truncate-split packing: two fp32 -> one uint holding 2 bf16 (hi parts),
// and residual lo parts. Truncation keeps residual exactly representable.
__device__ __forceinline__ void split2(float a, float b,
                                       unsigned int& hi, unsigned int& lo) {
  unsigned int ua = __float_as_uint(a), ub = __float_as_uint(b);
  unsigned int ha = ua & 0xFFFF0000u,  hb = ub & 0xFFFF0000u;
  float ra = a - __uint_as_float(ha);
  float rb = b - __uint_as_float(hb);
  hi = (ha >> 16) | hb;
  lo = (__float_as_uint(ra) >> 16) | (__float_as_uint(rb) & 0xFFFF0000u);
}

// RNE round fp32 -> bf16
__device__ __forceinline__ unsigned short rne_bf16(float h) {
  unsigned int u = __float_as_uint(h);
  return (unsigned short)((u + 0x7FFFu + ((u >> 16) & 1u)) >> 16);
}

// ---------------------------------------------------------------------------
// prep_w1: repack W1 [64, KTOT] fp32 into split-bf16 per-lane fragment layout.
// chunk = t*16 + it*4 + kh*2 + kt2 ; within chunk: [lane(64)][hi8|lo8] ushort.
// ---------------------------------------------------------------------------
__global__ __launch_bounds__(256) void prep_w1(
    const float* __restrict__ W1, unsigned short* __restrict__ W1p)
{
  const int idx   = blockIdx.x * 256 + threadIdx.x;  // 229376 total
  const int lane  = idx & 63;
  const int chunk = idx >> 6;           // t*16 + it*4 + kh*2 + kt2
  const int kt2   = chunk & 1;
  const int kh    = (chunk >> 1) & 1;
  const int it    = (chunk >> 2) & 3;
  const int t     = chunk >> 4;
  const int row   = it * 16 + (lane & 15);
  const int col   = t * 128 + kh * 64 + kt2 * 32 + (lane >> 4) * 8;
  const float* src = W1 + (size_t)row * KTOT + col;
  union { bf16x8 v; unsigned int u[4]; } hi, lo;
  #pragma unroll
  for (int p = 0; p < 4; ++p) split2(src[2 * p], src[2 * p + 1], hi.u[p], lo.u[p]);
  unsigned short* dst = W1p + (size_t)chunk * 1024 + lane * 16;
  *(bf16x8*)dst       = hi.v;
  *(bf16x8*)(dst + 8) = lo.v;
}

// ---------------------------------------------------------------------------
// Fused MFMA LSTM + GEMM1, one barrier per step. R10: EXACT R8 numerics
// (2-pass split-bf16 W_hh hi+lo, 2-pass W1, h as RNE bf16 — R8 passed all
// checks at absmax 1.22e-4; R9's 1-pass W_hh diverged post-timing, cause
// unexplained, axis abandoned). New in R10 (numerics-preserving):
//  * split accumulation chains (acc=hi-chain, acc2=lo-chain; facc/facc2):
//    serial MFMA dependency depth 8 -> 4 on the barrier-coupled critical path
//  * t=0 peeled: h0=0 so step 0 is bias+wih*x only; hot loop has no guards
// ---------------------------------------------------------------------------
__attribute__((amdgpu_waves_per_eu(2, 2)))
__global__ __launch_bounds__(512) void lstm_fused(
    const float* __restrict__ x,      // [NSEQ, TSEQ]
    const float* __restrict__ W_ih,   // [512, 1]
    const float* __restrict__ W_hh,   // [512, 128]
    const float* __restrict__ b_ih,   // [512]
    const float* __restrict__ b_hh,   // [512]
    const unsigned short* __restrict__ W1p,  // packed split-bf16 W1
    float* __restrict__ feats)        // [NSEQ, 64]
{
  const int tid = threadIdx.x;
  const int w   = tid >> 6;          // wave 0..7
  const int l   = tid & 63;          // lane
  const int lm  = l & 15;            // seq col n (D/B); A-frag row
  const int lq  = l >> 4;            // quad
  const int n0  = blockIdx.x * NB;

  __shared__ float s_x[NB][228];                         // padded: bank spread
  __shared__ int   s_fz[NB];
  __shared__ int   s_len[NB];
  __shared__ int   s_maxlen;
  // h B-fragments (plain bf16), double-buffered:
  // s_hb[buf][kt][quad*16+n][j] = bf16(h[unit kt*32+quad*8+j][seq n])
  __shared__ __align__(16) unsigned short s_hb[2][4][64][8];   // 8 KB
  __shared__ __align__(16) float s_red[2][4][64][4];     // feats partials

  // ---- stage x (coalesced: 32 threads per sequence), find first zero
  if (tid < NB) s_fz[tid] = TSEQ;
  __syncthreads();
  {
    const int n = tid >> 5, j = tid & 31;
    const float* xrow = x + (size_t)(n0 + n) * TSEQ;
    #pragma unroll
    for (int i = 0; i < 7; ++i) {
      int t = j + 32 * i;
      float v = xrow[t];
      s_x[n][t] = v;
      if (v == 0.0f) atomicMin(&s_fz[n], t);
    }
  }
  __syncthreads();
  if (tid < NB) {
    int fz = s_fz[tid];
    s_len[tid] = (fz == 0 || fz >= TSEQ) ? TSEQ : fz + 1;  // reference quirk
  }
  __syncthreads();
  if (tid == 0) {
    int m = 0;
    for (int n = 0; n < NB; ++n) m = max(m, s_len[n]);
    s_maxlen = m;
  }
  __syncthreads();
  const int maxlen = s_maxlen;
  const int len_lm = s_len[lm];      // len of the seq this lane updates/owns

  // ---- load LSTM A-fragments (W' permuted, split hi/lo) + per-lane consts
  bf16x8 whi[4][4], wlo[4][4];       // [mt][kt]
  #pragma unroll
  for (int mt = 0; mt < 4; ++mt) {
    const int MT   = w * 4 + mt;
    const int orow = (lm & 3) * 128 + MT * 4 + (lm >> 2);  // W' row permutation
    const float* wr = W_hh + (size_t)orow * HID;
    #pragma unroll
    for (int kt = 0; kt < 4; ++kt) {
      const int k0 = kt * 32 + lq * 8;
      union { bf16x8 v; unsigned int u[4]; } hi, lo;
      #pragma unroll
      for (int p = 0; p < 4; ++p)
        split2(wr[k0 + 2 * p], wr[k0 + 2 * p + 1], hi.u[p], lo.u[p]);
      whi[mt][kt] = hi.v;
      wlo[mt][kt] = lo.v;
    }
  }
  float bias_[4][4], wih_[4][4], c_[4];
  #pragma unroll
  for (int mt = 0; mt < 4; ++mt) {
    const int u_ = (w * 4 + mt) * 4 + lq;
    c_[mt] = 0.0f;
    #pragma unroll
    for (int r = 0; r < 4; ++r) {
      const int g = r * 128 + u_;       // r: 0=i 1=f 2=g~ 3=o
      bias_[mt][r] = b_ih[g] + b_hh[g];
      wih_[mt][r]  = W_ih[g];
    }
  }
  // ---- GEMM1 per-wave constants: wave w owns i-tile it = w>>1, kt-half kh
  const int it = w >> 1;
  const int kh = w & 1;
  const unsigned short* w1p_base = W1p + ((size_t)it * 4 + kh * 2) * 1024 + l * 16;
  f32x4 facc  = {0.f, 0.f, 0.f, 0.f};
  f32x4 facc2 = {0.f, 0.f, 0.f, 0.f};

  // ---- peeled t=0: h_{-1}=0 -> gates = bias + wih*x0, no MFMA, no GEMM1
  {
    const float xv = s_x[lm][0];
    #pragma unroll
    for (int mt = 0; mt < 4; ++mt) {
      float a0 = fmaf(wih_[mt][0], xv, bias_[mt][0]);
      float a1 = fmaf(wih_[mt][1], xv, bias_[mt][1]);
      float a2 = fmaf(wih_[mt][2], xv, bias_[mt][2]);
      float a3 = fmaf(wih_[mt][3], xv, bias_[mt][3]);
      float i_ = fast_sigmoid(a0);
      float f_ = fast_sigmoid(a1);
      float g_ = fast_tanh(a2);
      float o_ = fast_sigmoid(a3);
      c_[mt] = fmaf(f_, c_[mt], i_ * g_);
      float h_ = o_ * fast_tanh(c_[mt]);
      h_ = (0 < len_lm) ? h_ : 0.0f;
      const int u_ = 16 * w + 4 * mt + lq;
      s_hb[1][u_ >> 5][((u_ >> 3) & 3) * 16 + lm][u_ & 7] = rne_bf16(h_);
    }
    __syncthreads();
  }

  for (int t = 1; t < maxlen; ++t) {
    const int p = t & 1;
    // W1 slice (t-1) fragments: 2 coalesced 32B loads
    bf16x8 w1hi[2], w1lo[2];
    {
      const unsigned short* p0 = w1p_base + (size_t)(t - 1) * 16384;
      w1hi[0] = *(const bf16x8*)p0;
      w1lo[0] = *(const bf16x8*)(p0 + 8);
      w1hi[1] = *(const bf16x8*)(p0 + 1024);
      w1lo[1] = *(const bf16x8*)(p0 + 1024 + 8);
    }
    const float xv = s_x[lm][t];
    f32x4 acc[4], acc2[4];
    #pragma unroll
    for (int mt = 0; mt < 4; ++mt)
      #pragma unroll
      for (int r = 0; r < 4; ++r) {
        acc[mt][r]  = fmaf(wih_[mt][r], xv, bias_[mt][r]);
        acc2[mt][r] = 0.0f;
      }
    // kt-outer: one b128 read per kt; SPLIT chains (hi->acc, lo->acc2)
    #pragma unroll
    for (int kt = 0; kt < 4; ++kt) {
      bf16x8 bh = *(const bf16x8*)&s_hb[p][kt][l][0];
      #pragma unroll
      for (int mt = 0; mt < 4; ++mt) {
        acc[mt]  = __builtin_amdgcn_mfma_f32_16x16x32_bf16(whi[mt][kt], bh, acc[mt],  0, 0, 0);
        acc2[mt] = __builtin_amdgcn_mfma_f32_16x16x32_bf16(wlo[mt][kt], bh, acc2[mt], 0, 0, 0);
      }
      if ((kt >> 1) == kh) {            // wave-uniform
        const int kt2 = kt & 1;
        facc  = __builtin_amdgcn_mfma_f32_16x16x32_bf16(w1hi[kt2], bh, facc,  0, 0, 0);
        facc2 = __builtin_amdgcn_mfma_f32_16x16x32_bf16(w1lo[kt2], bh, facc2, 0, 0, 0);
      }
    }
    // in-lane LSTM update + direct bf16 frag write to buffer p^1
    #pragma unroll
    for (int mt = 0; mt < 4; ++mt) {
      float i_ = fast_sigmoid(acc[mt][0] + acc2[mt][0]);
      float f_ = fast_sigmoid(acc[mt][1] + acc2[mt][1]);
      float g_ = fast_tanh(acc[mt][2] + acc2[mt][2]);
      float o_ = fast_sigmoid(acc[mt][3] + acc2[mt][3]);
      c_[mt] = fmaf(f_, c_[mt], i_ * g_);
      float h_ = o_ * fast_tanh(c_[mt]);
      h_ = (t < len_lm) ? h_ : 0.0f;      // mask: matches reference hs zeroing
      const int u_ = 16 * w + 4 * mt + lq;  // unit this lane owns
      s_hb[p ^ 1][u_ >> 5][((u_ >> 3) & 3) * 16 + lm][u_ & 7] = rne_bf16(h_);
    }
    __syncthreads();
  }

  // ---- epilogue: GEMM1 for the final slice (maxlen-1) with h_{maxlen-1}
  {
    const int pe = maxlen & 1;
    const unsigned short* p0 = w1p_base + (size_t)(maxlen - 1) * 16384;
    bf16x8 w1hi[2], w1lo[2];
    w1hi[0] = *(const bf16x8*)p0;
    w1lo[0] = *(const bf16x8*)(p0 + 8);
    w1hi[1] = *(const bf16x8*)(p0 + 1024);
    w1lo[1] = *(const bf16x8*)(p0 + 1024 + 8);
    #pragma unroll
    for (int kt2 = 0; kt2 < 2; ++kt2) {
      const int kt = 2 * kh + kt2;
      bf16x8 bh = *(const bf16x8*)&s_hb[pe][kt][l][0];
      facc  = __builtin_amdgcn_mfma_f32_16x16x32_bf16(w1hi[kt2], bh, facc,  0, 0, 0);
      facc2 = __builtin_amdgcn_mfma_f32_16x16x32_bf16(w1lo[kt2], bh, facc2, 0, 0, 0);
    }
    facc = facc + facc2;
  }

  // ---- reduce kt-halves across wave pairs, write feats[n][i]
  *(f32x4*)&s_red[kh][it][l][0] = facc;
  __syncthreads();
  {
    const int n     = tid >> 5;          // 0..15
    const int ipair = tid & 31;          // 0..31
    const int i0    = ipair * 2;
    const int tile  = i0 >> 4;
    const int lqi   = (i0 & 15) >> 2;
    const int r0    = i0 & 3;            // 0 or 2
    const int lane  = lqi * 16 + n;
    float v0 = s_red[0][tile][lane][r0]     + s_red[1][tile][lane][r0];
    float v1 = s_red[0][tile][lane][r0 + 1] + s_red[1][tile][lane][r0 + 1];
    *(float2*)(feats + (size_t)(n0 + n) * INTER + i0) = make_float2(v0, v1);
  }
}

// ---------------------------------------------------------------------------
// GEMM2: out[b][m] = b2[m] + sum_{s,i} (feats[b*20+s][i]+b1[i]) * W2[m][s*64+i]
// ---------------------------------------------------------------------------
__global__ __launch_bounds__(64) void gemm2_kernel(
    const float* __restrict__ feats,  // [NSEQ, 64]
    const float* __restrict__ b1,     // [64]
    const float* __restrict__ W2,     // [2, 1280]
    const float* __restrict__ b2,     // [2]
    float* __restrict__ out)          // [64, 2]
{
  const int b = blockIdx.x;
  const int i = threadIdx.x;
  const float bi = b1[i];
  float acc0 = 0.f, acc1 = 0.f;
  #pragma unroll
  for (int s = 0; s < SUB; ++s) {
    float f = feats[(size_t)(b * SUB + s) * INTER + i] + bi;
    acc0 = fmaf(f, W2[s * INTER + i], acc0);
    acc1 = fmaf(f, W2[1280 + s * INTER + i], acc1);
  }
  #pragma unroll
  for (int off = 32; off > 0; off >>= 1) {
    acc0 += __shfl_down(acc0, off);
    acc1 += __shfl_down(acc1, off);
  }
  if (i == 0) {
    out[b * 2 + 0] = acc0 + b2[0];
    out[b * 2 + 1] = acc1 + b2[1];
  }
}

// ---------------------------------------------------------------------------
extern "C" void kernel_launch(void* const* d_in, const int* in_sizes, int n_in,
                              void* d_out, int out_size, void* d_ws, size_t ws_size,
                              hipStream_t stream) {
  const float* x    = (const float*)d_in[0];
  // d_in[1] = metadata: unused by the reference
  const float* W_ih = (const float*)d_in[2];
  const float* W_hh = (const float*)d_in[3];
  const float* b_ih = (const float*)d_in[4];
  const float* b_hh = (const float*)d_in[5];
  const float* W1   = (const float*)d_in[6];
  const float* b1   = (const float*)d_in[7];
  const float* W2   = (const float*)d_in[8];
  const float* b2   = (const float*)d_in[9];
  float* out = (float*)d_out;

  // workspace: W1p packed split-bf16 [229376*16 ushort = 7.34 MB] + feats [327 KB]
  unsigned short* W1p = (unsigned short*)d_ws;
  float* feats = (float*)((char*)d_ws + (size_t)229376 * 16 * sizeof(unsigned short));

  prep_w1<<<896, 256, 0, stream>>>(W1, W1p);
  lstm_fused<<<NSEQ / NB, 512, 0, stream>>>(x, W_ih, W_hh, b_ih, b_hh, W1p, feats);
  gemm2_kernel<<<64, 64, 0, stream>>>(feats, b1, W2, b2, out);
}

// Round 12
// 401.697 us; speedup vs baseline: 1.0214x; 1.0214x over previous
//
#include <hip/hip_runtime.h>
#include <cstdint>

// Problem constants (from reference)
#define TSEQ 224
#define HID 128
#define NSEQ 1280           // BATCHES*SUB = 64*20
#define KTOT (TSEQ*HID)     // 28672
#define NB 16               // sequences per LSTM block
#define INTER 64
#define SUB 20

typedef short bf16x8 __attribute__((ext_vector_type(8)));
typedef float f32x4  __attribute__((ext_vector_type(4)));

__device__ __forceinline__ float fast_sigmoid(float a) {
  float e = __expf(-a);
  return __builtin_amdgcn_rcpf(1.0f + e);
}
__device__ __forceinline__ float fast_tanh(float a) {
  float e = __expf(-2.0f * a);
  return fmaf(2.0f, __builtin_amdgcn_rcpf(1.0f + e), -1.0f);
}

// Truncate-split packing: two fp32 -> one uint holding 2 bf16 (hi parts),
// and residual lo parts. Truncation keeps residual exactly representable.
__device__ __forceinline__ void split2(float a, float b,
                                       unsigned int& hi, unsigned int& lo) {
  unsigned int ua = __float_as_uint(a), ub = __float_as_uint(b);
  unsigned int ha = ua & 0xFFFF0000u,  hb = ub & 0xFFFF0000u;
  float ra = a - __uint_as_float(ha);
  float rb = b - __uint_as_float(hb);
  hi = (ha >> 16) | hb;
  lo = (__float_as_uint(ra) >> 16) | (__float_as_uint(rb) & 0xFFFF0000u);
}

// RNE round fp32 -> bf16
__device__ __forceinline__ unsigned short rne_bf16(float h) {
  unsigned int u = __float_as_uint(h);
  return (unsigned short)((u + 0x7FFFu + ((u >> 16) & 1u)) >> 16);
}

// ---------------------------------------------------------------------------
// prep_w1 (R12 rewrite): same OUTPUT as before (bit-identical W1p), but
// coalesced on both sides via an LDS tile transpose. Old version read W1
// with a 114,688-B stride across lanes (R5's L1-set-aliasing pathology).
// Block = 256 threads; grid 224 = 4 row-groups (it) x 56 t-groups (4 t each).
// Phase 1: stage rows [it*16,+16) x cols [tb*512,+512) with coalesced
// float4 reads. Phase 2: emit 16 chunks; lane writes 32 B at lane*16 ushorts
// -> consecutive lanes contiguous. LDS row pad +4 floats: reads across
// r15 land 2-per-bank (free).
// ---------------------------------------------------------------------------
__global__ __launch_bounds__(256) void prep_w1(
    const float* __restrict__ W1, unsigned short* __restrict__ W1p)
{
  const int tid = threadIdx.x;
  const int it  = blockIdx.x & 3;        // row group: rows it*16..+16
  const int tb  = blockIdx.x >> 2;       // t group: t in [tb*4, tb*4+4)

  __shared__ float s_w[16][516];         // 16 rows x 512 cols (+4 pad)

  // phase 1: coalesced load of the 16x512 tile
  #pragma unroll
  for (int k = 0; k < 8; ++k) {
    int flat  = k * 256 + tid;           // 0..2047 float4s
    int row16 = flat >> 7;               // /128
    int colq  = flat & 127;
    float4 v = *(const float4*)(W1 + (size_t)(it * 16 + row16) * KTOT
                                + tb * 512 + colq * 4);
    *(float4*)&s_w[row16][colq * 4] = v;
  }
  __syncthreads();

  // phase 2: each thread emits 4 (chunk,lane) cells of 16 ushorts
  #pragma unroll
  for (int j = 0; j < 4; ++j) {
    int q      = j * 256 + tid;          // 0..1023
    int cl     = q >> 6;                 // chunk_local 0..15
    int lane   = q & 63;
    int tloc   = cl >> 2;
    int kh     = (cl >> 1) & 1;
    int kt2    = cl & 1;
    int lq     = lane >> 4;
    int r15    = lane & 15;
    const float* src = &s_w[r15][tloc * 128 + kh * 64 + kt2 * 32 + lq * 8];
    union { bf16x8 v; unsigned int u[4]; } hi, lo;
    #pragma unroll
    for (int p = 0; p < 4; ++p) split2(src[2 * p], src[2 * p + 1], hi.u[p], lo.u[p]);
    const int chunk = (tb * 4 + tloc) * 16 + it * 4 + kh * 2 + kt2;
    unsigned short* dst = W1p + (size_t)chunk * 1024 + lane * 16;
    *(bf16x8*)dst       = hi.v;
    *(bf16x8*)(dst + 8) = lo.v;
  }
}

// ---------------------------------------------------------------------------
// Fused MFMA LSTM + GEMM1 — VERBATIM R8 kernel (best passing: lstm 331 us,
// absmax 1.2207e-4, passed post-timing). R9 (1-pass W_hh) and R11 (W1p
// register prefetch) both failed correctness in ways unexplainable at source
// level; both changed the hot loop's register structure. That axis is
// abandoned — do not touch this kernel's loop body.
// ---------------------------------------------------------------------------
__attribute__((amdgpu_waves_per_eu(2, 2)))
__global__ __launch_bounds__(512) void lstm_fused(
    const float* __restrict__ x,      // [NSEQ, TSEQ]
    const float* __restrict__ W_ih,   // [512, 1]
    const float* __restrict__ W_hh,   // [512, 128]
    const float* __restrict__ b_ih,   // [512]
    const float* __restrict__ b_hh,   // [512]
    const unsigned short* __restrict__ W1p,  // packed split-bf16 W1
    float* __restrict__ feats)        // [NSEQ, 64]
{
  const int tid = threadIdx.x;
  const int w   = tid >> 6;          // wave 0..7
  const int l   = tid & 63;          // lane
  const int lm  = l & 15;            // seq col n (D/B); A-frag row
  const int lq  = l >> 4;            // quad
  const int n0  = blockIdx.x * NB;

  __shared__ float s_x[NB][228];                         // padded: bank spread
  __shared__ int   s_fz[NB];
  __shared__ int   s_len[NB];
  __shared__ int   s_maxlen;
  // h B-fragments (plain bf16), double-buffered:
  // s_hb[buf][kt][quad*16+n][j] = bf16(h[unit kt*32+quad*8+j][seq n])
  __shared__ __align__(16) unsigned short s_hb[2][4][64][8];   // 8 KB
  __shared__ __align__(16) float s_red[2][4][64][4];     // feats partials

  // ---- stage x (coalesced: 32 threads per sequence), find first zero
  if (tid < NB) s_fz[tid] = TSEQ;
  __syncthreads();
  {
    const int n = tid >> 5, j = tid & 31;
    const float* xrow = x + (size_t)(n0 + n) * TSEQ;
    #pragma unroll
    for (int i = 0; i < 7; ++i) {
      int t = j + 32 * i;
      float v = xrow[t];
      s_x[n][t] = v;
      if (v == 0.0f) atomicMin(&s_fz[n], t);
    }
  }
  // zero-init frag buffer 0 (h0 = 0): 4 KB
  ((uint2*)&s_hb[0][0][0][0])[tid] = make_uint2(0u, 0u);
  __syncthreads();
  if (tid < NB) {
    int fz = s_fz[tid];
    s_len[tid] = (fz == 0 || fz >= TSEQ) ? TSEQ : fz + 1;  // reference quirk
  }
  __syncthreads();
  if (tid == 0) {
    int m = 0;
    for (int n = 0; n < NB; ++n) m = max(m, s_len[n]);
    s_maxlen = m;
  }
  __syncthreads();
  const int maxlen = s_maxlen;
  const int len_lm = s_len[lm];      // len of the seq this lane updates/owns

  // ---- load LSTM A-fragments (W' permuted, split hi/lo) + per-lane consts
  bf16x8 whi[4][4], wlo[4][4];       // [mt][kt]
  #pragma unroll
  for (int mt = 0; mt < 4; ++mt) {
    const int MT   = w * 4 + mt;
    const int orow = (lm & 3) * 128 + MT * 4 + (lm >> 2);  // W' row permutation
    const float* wr = W_hh + (size_t)orow * HID;
    #pragma unroll
    for (int kt = 0; kt < 4; ++kt) {
      const int k0 = kt * 32 + lq * 8;
      union { bf16x8 v; unsigned int u[4]; } hi, lo;
      #pragma unroll
      for (int p = 0; p < 4; ++p)
        split2(wr[k0 + 2 * p], wr[k0 + 2 * p + 1], hi.u[p], lo.u[p]);
      whi[mt][kt] = hi.v;
      wlo[mt][kt] = lo.v;
    }
  }
  float bias_[4][4], wih_[4][4], c_[4];
  #pragma unroll
  for (int mt = 0; mt < 4; ++mt) {
    const int u_ = (w * 4 + mt) * 4 + lq;
    c_[mt] = 0.0f;
    #pragma unroll
    for (int r = 0; r < 4; ++r) {
      const int g = r * 128 + u_;       // r: 0=i 1=f 2=g~ 3=o
      bias_[mt][r] = b_ih[g] + b_hh[g];
      wih_[mt][r]  = W_ih[g];
    }
  }
  // ---- GEMM1 per-wave constants: wave w owns i-tile it = w>>1, kt-half kh
  const int it = w >> 1;
  const int kh = w & 1;
  const unsigned short* w1p_base = W1p + ((size_t)it * 4 + kh * 2) * 1024 + l * 16;
  f32x4 facc = {0.f, 0.f, 0.f, 0.f};

  for (int t = 0; t < maxlen; ++t) {
    const int p = t & 1;
    // W1 slice (t-1) fragments: 2 coalesced 32B loads (skip t=0: h_{-1}=0)
    bf16x8 w1hi[2], w1lo[2];
    if (t > 0) {
      const unsigned short* p0 = w1p_base + (size_t)(t - 1) * 16384;
      w1hi[0] = *(const bf16x8*)p0;
      w1lo[0] = *(const bf16x8*)(p0 + 8);
      w1hi[1] = *(const bf16x8*)(p0 + 1024);
      w1lo[1] = *(const bf16x8*)(p0 + 1024 + 8);
    }
    const float xv = s_x[lm][t];
    f32x4 acc[4];
    #pragma unroll
    for (int mt = 0; mt < 4; ++mt)
      #pragma unroll
      for (int r = 0; r < 4; ++r)
        acc[mt][r] = fmaf(wih_[mt][r], xv, bias_[mt][r]);
    // kt-outer: one b128 read per kt, 2-pass MFMA; GEMM1 folded in
    #pragma unroll
    for (int kt = 0; kt < 4; ++kt) {
      bf16x8 bh = *(const bf16x8*)&s_hb[p][kt][l][0];
      #pragma unroll
      for (int mt = 0; mt < 4; ++mt) {
        acc[mt] = __builtin_amdgcn_mfma_f32_16x16x32_bf16(whi[mt][kt], bh, acc[mt], 0, 0, 0);
        acc[mt] = __builtin_amdgcn_mfma_f32_16x16x32_bf16(wlo[mt][kt], bh, acc[mt], 0, 0, 0);
      }
      if (t > 0 && (kt >> 1) == kh) {
        const int kt2 = kt & 1;
        facc = __builtin_amdgcn_mfma_f32_16x16x32_bf16(w1hi[kt2], bh, facc, 0, 0, 0);
        facc = __builtin_amdgcn_mfma_f32_16x16x32_bf16(w1lo[kt2], bh, facc, 0, 0, 0);
      }
    }
    // in-lane LSTM update + direct bf16 frag write to buffer p^1
    #pragma unroll
    for (int mt = 0; mt < 4; ++mt) {
      float i_ = fast_sigmoid(acc[mt][0]);
      float f_ = fast_sigmoid(acc[mt][1]);
      float g_ = fast_tanh(acc[mt][2]);
      float o_ = fast_sigmoid(acc[mt][3]);
      c_[mt] = fmaf(f_, c_[mt], i_ * g_);
      float h_ = o_ * fast_tanh(c_[mt]);
      h_ = (t < len_lm) ? h_ : 0.0f;      // mask: matches reference hs zeroing
      const int u_ = 16 * w + 4 * mt + lq;  // unit this lane owns
      s_hb[p ^ 1][u_ >> 5][((u_ >> 3) & 3) * 16 + lm][u_ & 7] = rne_bf16(h_);
    }
    __syncthreads();
  }

  // ---- epilogue: GEMM1 for the final slice (maxlen-1) with h_{maxlen-1}
  {
    const int pe = maxlen & 1;
    const unsigned short* p0 = w1p_base + (size_t)(maxlen - 1) * 16384;
    bf16x8 w1hi[2], w1lo[2];
    w1hi[0] = *(const bf16x8*)p0;
    w1lo[0] = *(const bf16x8*)(p0 + 8);
    w1hi[1] = *(const bf16x8*)(p0 + 1024);
    w1lo[1] = *(const bf16x8*)(p0 + 1024 + 8);
    #pragma unroll
    for (int kt2 = 0; kt2 < 2; ++kt2) {
      const int kt = 2 * kh + kt2;
      bf16x8 bh = *(const bf16x8*)&s_hb[pe][kt][l][0];
      facc = __builtin_amdgcn_mfma_f32_16x16x32_bf16(w1hi[kt2], bh, facc, 0, 0, 0);
      facc = __builtin_amdgcn_mfma_f32_16x16x32_bf16(w1lo[kt2], bh, facc, 0, 0, 0);
    }
  }

  // ---- reduce kt-halves across wave pairs, write feats[n][i]
  *(f32x4*)&s_red[kh][it][l][0] = facc;
  __syncthreads();
  {
    const int n     = tid >> 5;          // 0..15
    const int ipair = tid & 31;          // 0..31
    const int i0    = ipair * 2;
    const int tile  = i0 >> 4;
    const int lqi   = (i0 & 15) >> 2;
    const int r0    = i0 & 3;            // 0 or 2
    const int lane  = lqi * 16 + n;
    float v0 = s_red[0][tile][lane][r0]     + s_red[1][tile][lane][r0];
    float v1 = s_red[0][tile][lane][r0 + 1] + s_red[1][tile][lane][r0 + 1];
    *(float2*)(feats + (size_t)(n0 + n) * INTER + i0) = make_float2(v0, v1);
  }
}

// ---------------------------------------------------------------------------
// GEMM2: out[b][m] = b2[m] + sum_{s,i} (feats[b*20+s][i]+b1[i]) * W2[m][s*64+i]
// ---------------------------------------------------------------------------
__global__ __launch_bounds__(64) void gemm2_kernel(
    const float* __restrict__ feats,  // [NSEQ, 64]
    const float* __restrict__ b1,     // [64]
    const float* __restrict__ W2,     // [2, 1280]
    const float* __restrict__ b2,     // [2]
    float* __restrict__ out)          // [64, 2]
{
  const int b = blockIdx.x;
  const int i = threadIdx.x;
  const float bi = b1[i];
  float acc0 = 0.f, acc1 = 0.f;
  #pragma unroll
  for (int s = 0; s < SUB; ++s) {
    float f = feats[(size_t)(b * SUB + s) * INTER + i] + bi;
    acc0 = fmaf(f, W2[s * INTER + i], acc0);
    acc1 = fmaf(f, W2[1280 + s * INTER + i], acc1);
  }
  #pragma unroll
  for (int off = 32; off > 0; off >>= 1) {
    acc0 += __shfl_down(acc0, off);
    acc1 += __shfl_down(acc1, off);
  }
  if (i == 0) {
    out[b * 2 + 0] = acc0 + b2[0];
    out[b * 2 + 1] = acc1 + b2[1];
  }
}

// ---------------------------------------------------------------------------
extern "C" void kernel_launch(void* const* d_in, const int* in_sizes, int n_in,
                              void* d_out, int out_size, void* d_ws, size_t ws_size,
                              hipStream_t stream) {
  const float* x    = (const float*)d_in[0];
  // d_in[1] = metadata: unused by the reference
  const float* W_ih = (const float*)d_in[2];
  const float* W_hh = (const float*)d_in[3];
  const float* b_ih = (const float*)d_in[4];
  const float* b_hh = (const float*)d_in[5];
  const float* W1   = (const float*)d_in[6];
  const float* b1   = (const float*)d_in[7];
  const float* W2   = (const float*)d_in[8];
  const float* b2   = (const float*)d_in[9];
  float* out = (float*)d_out;

  // workspace: W1p packed split-bf16 [229376*16 ushort = 7.34 MB] + feats [327 KB]
  unsigned short* W1p = (unsigned short*)d_ws;
  float* feats = (float*)((char*)d_ws + (size_t)229376 * 16 * sizeof(unsigned short));

  prep_w1<<<224, 256, 0, stream>>>(W1, W1p);
  lstm_fused<<<NSEQ / NB, 512, 0, stream>>>(x, W_ih, W_hh, b_ih, b_hh, W1p, feats);
  gemm2_kernel<<<64, 64, 0, stream>>>(feats, b1, W2, b2, out);
}